// Round 9
// baseline (77.562 us; speedup 1.0000x reference)
//
#include <hip/hip_runtime.h>
#include <math.h>

// Problem constants
#define NB 128     // batch
#define NR 1152    // routes
#define NC 10      // capsules
#define NCHK 24    // partial chunks per capsule (route-chunks of 48)

typedef __attribute__((ext_vector_type(8))) short bf16x8;
typedef __attribute__((ext_vector_type(16))) float f32x16;

__device__ __forceinline__ unsigned pk_bf16(float a, float b) {
    unsigned r;
    asm("v_cvt_pk_bf16_f32 %0, %1, %2" : "=v"(r) : "v"(a), "v"(b));
    return r;
}

// ------------------------------------------------------------------
// pass_y: fused bf16x3 + 32x32x16 MFMA pred + route reduction + (NEW)
// folded merge/squash epilogue via per-capsule atomic "last block merges".
// Grid 240 = (10 c x 24 rch of 48 routes), XCD-chunked. 512 thr = 8 waves:
// wave = (h = route-quarter of 12, bp = batch-half).
// A = W (M=o), B = x (N=b). C: col(l&31)=b, row(reg&3)+8*(reg>>2)+4*hi1=o.
// MODE 0: uniform sum; x read direct (scattered); owner blocks write xts
//         (bf16 hi/lo planes, MFMA-ready, 512B-coalesced).
// MODE 1/2: x fragments loaded straight from xts (no convert VALU);
//         d = pred.ov, e = exp(d-20), Z += e, acc += e*pred.
// Tail: 8-wave XOR-swizzled LDS merge -> ps chunk via agent-scope
// write-through atomic stores; __syncthreads (drains vmcnt); one relaxed
// agent fetch_add per block; last block (old==23) merges all 24 chunks of
// its capsule with agent atomic loads (L2-bypass -> no staleness), squashes,
// and writes oacc (MODE 0), oacc += (MODE 1), or dout (MODE 2).
// No L2 wb/inv anywhere -> W/x L2 residency preserved across passes.
// ------------------------------------------------------------------
template<int MODE>
__global__ __launch_bounds__(512, 2) void pass_y(const float* __restrict__ x,
                                                 const float* __restrict__ W,
                                                 unsigned* __restrict__ xts,
                                                 float* __restrict__ oacc,
                                                 float* __restrict__ dout,
                                                 float* __restrict__ ps,
                                                 float* __restrict__ pz,
                                                 int* __restrict__ cnt)
{
    __shared__ float lds[16384];   // 64 KB
    __shared__ int lastFlag;
    const int pb = blockIdx.x;
    const int lin = (pb & 7) * 30 + (pb >> 3);   // chunked XCD swizzle (240 = 8*30)
    const int rch = lin / 10;
    const int c   = lin - rch * 10;
    const int t = threadIdx.x;
    const int w = t >> 6, l = t & 63;
    const int h = w >> 1, bp = w & 1;
    const int lo5 = l & 31, hi1 = l >> 5;
    const int r0 = rch * 48 + h * 12;

    if (MODE >= 1) {
        for (int idx = t; idx < 4096; idx += 512)
            lds[(idx >> 5) * 33 + (idx & 31)] = oacc[(size_t)c * 4096 + idx];
    }
    __syncthreads();

    float ov0[16], ov1[16];
    if (MODE >= 1) {
#pragma unroll
        for (int j = 0; j < 16; ++j) {
            int orow = (j & 3) + 8 * (j >> 2) + 4 * hi1;
            ov0[j] = lds[(bp * 64 + lo5) * 33 + orow];
            ov1[j] = lds[(bp * 64 + 32 + lo5) * 33 + orow];
        }
    }

    f32x16 acc0, acc1, zz;
#pragma unroll
    for (int j = 0; j < 16; ++j) { acc0[j] = 0.f; acc1[j] = 0.f; zz[j] = 0.f; }
    float Z0 = 0.f, Z1 = 0.f;

    // W element (r, i=hi1*8+j, o=lo5)
    const float* wb  = W + ((size_t)(c * NR + r0) * 16 + hi1 * 8) * 32 + lo5;
    // direct-x pointers (MODE 0)
    const float* xp0 = x + ((size_t)(bp * 64 + lo5) * NR + r0) * 16 + hi1 * 8;
    const float* xp1 = x + ((size_t)(bp * 64 + 32 + lo5) * NR + r0) * 16 + hi1 * 8;
    // xts uint4-unit addressing: ((r*2+hi1)*2 + plane)*128 + b
    uint4* xt4 = (uint4*)xts;
    const int bq0 = bp * 64 + lo5, bq1 = bq0 + 32;

    for (int rr = 0; rr < 12; ++rr) {
        // ---- W fragment: 8 lane-coalesced f32 -> hi/lo bf16 planes ----
        float wv[8];
#pragma unroll
        for (int j = 0; j < 8; ++j) wv[j] = wb[(size_t)rr * 512 + j * 32];
        union U { uint4 q; unsigned u[4]; bf16x8 v; };
        U Ah, Al, Xh0, Xl0, Xh1, Xl1;
#pragma unroll
        for (int j = 0; j < 4; ++j) Ah.u[j] = pk_bf16(wv[2*j], wv[2*j+1]);
#pragma unroll
        for (int j = 0; j < 4; ++j) {
            float g0 = __uint_as_float(Ah.u[j] << 16);
            float g1 = __uint_as_float(Ah.u[j] & 0xffff0000u);
            Al.u[j] = pk_bf16(wv[2*j] - g0, wv[2*j+1] - g1);
        }
        // ---- x fragments ----
        const size_t rb4 = ((size_t)((r0 + rr) * 2 + hi1) * 2) * 128;
        if (MODE == 0) {
            float4 u0 = *(const float4*)(xp0 + rr * 16);
            float4 u1 = *(const float4*)(xp0 + rr * 16 + 4);
            float4 v0 = *(const float4*)(xp1 + rr * 16);
            float4 v1 = *(const float4*)(xp1 + rr * 16 + 4);
            float xv0[8] = {u0.x,u0.y,u0.z,u0.w, u1.x,u1.y,u1.z,u1.w};
            float xv1[8] = {v0.x,v0.y,v0.z,v0.w, v1.x,v1.y,v1.z,v1.w};
#pragma unroll
            for (int j = 0; j < 4; ++j) Xh0.u[j] = pk_bf16(xv0[2*j], xv0[2*j+1]);
#pragma unroll
            for (int j = 0; j < 4; ++j) {
                float g0 = __uint_as_float(Xh0.u[j] << 16);
                float g1 = __uint_as_float(Xh0.u[j] & 0xffff0000u);
                Xl0.u[j] = pk_bf16(xv0[2*j] - g0, xv0[2*j+1] - g1);
            }
#pragma unroll
            for (int j = 0; j < 4; ++j) Xh1.u[j] = pk_bf16(xv1[2*j], xv1[2*j+1]);
#pragma unroll
            for (int j = 0; j < 4; ++j) {
                float g0 = __uint_as_float(Xh1.u[j] << 16);
                float g1 = __uint_as_float(Xh1.u[j] & 0xffff0000u);
                Xl1.u[j] = pk_bf16(xv1[2*j] - g0, xv1[2*j+1] - g1);
            }
            // distributed xts write: this block owns routes (h*12+rr)%10 == c
            if (((h * 12 + rr) % 10) == c) {
                xt4[rb4 + bq0]       = Xh0.q;
                xt4[rb4 + 128 + bq0] = Xl0.q;
                xt4[rb4 + bq1]       = Xh1.q;
                xt4[rb4 + 128 + bq1] = Xl1.q;
            }
        } else {
            Xh0.q = xt4[rb4 + bq0];
            Xl0.q = xt4[rb4 + 128 + bq0];
            Xh1.q = xt4[rb4 + bq1];
            Xl1.q = xt4[rb4 + 128 + bq1];
        }

        if (MODE == 0) {
            acc0 = __builtin_amdgcn_mfma_f32_32x32x16_bf16(Ah.v, Xh0.v, acc0, 0, 0, 0);
            acc0 = __builtin_amdgcn_mfma_f32_32x32x16_bf16(Al.v, Xh0.v, acc0, 0, 0, 0);
            acc0 = __builtin_amdgcn_mfma_f32_32x32x16_bf16(Ah.v, Xl0.v, acc0, 0, 0, 0);
            acc1 = __builtin_amdgcn_mfma_f32_32x32x16_bf16(Ah.v, Xh1.v, acc1, 0, 0, 0);
            acc1 = __builtin_amdgcn_mfma_f32_32x32x16_bf16(Al.v, Xh1.v, acc1, 0, 0, 0);
            acc1 = __builtin_amdgcn_mfma_f32_32x32x16_bf16(Ah.v, Xl1.v, acc1, 0, 0, 0);
        } else {
            f32x16 q0, q1;
            q0 = __builtin_amdgcn_mfma_f32_32x32x16_bf16(Ah.v, Xh0.v, zz, 0, 0, 0);
            q1 = __builtin_amdgcn_mfma_f32_32x32x16_bf16(Ah.v, Xh1.v, zz, 0, 0, 0);
            q0 = __builtin_amdgcn_mfma_f32_32x32x16_bf16(Al.v, Xh0.v, q0, 0, 0, 0);
            q1 = __builtin_amdgcn_mfma_f32_32x32x16_bf16(Al.v, Xh1.v, q1, 0, 0, 0);
            q0 = __builtin_amdgcn_mfma_f32_32x32x16_bf16(Ah.v, Xl0.v, q0, 0, 0, 0);
            q1 = __builtin_amdgcn_mfma_f32_32x32x16_bf16(Ah.v, Xl1.v, q1, 0, 0, 0);
            float d0 = 0.f, d1 = 0.f;
#pragma unroll
            for (int j = 0; j < 16; ++j) {
                d0 = fmaf(q0[j], ov0[j], d0);
                d1 = fmaf(q1[j], ov1[j], d1);
            }
            d0 += __shfl_xor(d0, 32);
            d1 += __shfl_xor(d1, 32);
            float e0 = __expf(d0 - 20.0f);
            float e1 = __expf(d1 - 20.0f);
            Z0 += e0; Z1 += e1;
#pragma unroll
            for (int j = 0; j < 16; ++j) {
                acc0[j] = fmaf(e0, q0[j], acc0[j]);
                acc1[j] = fmaf(e1, q1[j], acc1[j]);
            }
        }
    }

    // ---- 8-wave LDS merge (4 h-slices; b-halves disjoint) ----
    const int b0 = bp * 64 + lo5, b1 = b0 + 32;
    __syncthreads();
#pragma unroll
    for (int j = 0; j < 16; ++j) {
        int orow = (j & 3) + 8 * (j >> 2) + 4 * hi1;
        lds[h * 4096 + b0 * 32 + (orow ^ lo5)] = acc0[j];
        lds[h * 4096 + b1 * 32 + (orow ^ lo5)] = acc1[j];
    }
    __syncthreads();
    // ps chunk via agent-scope write-through atomic stores
    float* po = ps + (size_t)(c * NCHK + rch) * 4096;
    for (int idx = t; idx < 4096; idx += 512) {
        int b = idx >> 5, o = idx & 31;
        float s = 0.f;
#pragma unroll
        for (int hh = 0; hh < 4; ++hh)
            s += lds[hh * 4096 + b * 32 + (o ^ (b & 31))];
        __hip_atomic_store(po + idx, s, __ATOMIC_RELAXED, __HIP_MEMORY_SCOPE_AGENT);
    }
    if (MODE >= 1) {
        __syncthreads();
        if (l < 32) {
            lds[h * 128 + bp * 64 + lo5] = Z0;
            lds[h * 128 + bp * 64 + 32 + lo5] = Z1;
        }
        __syncthreads();
        if (t < 128) {
            float z = lds[t] + lds[128 + t] + lds[256 + t] + lds[384 + t];
            __hip_atomic_store(pz + (size_t)(c * NCHK + rch) * 128 + t, z,
                               __ATOMIC_RELAXED, __HIP_MEMORY_SCOPE_AGENT);
        }
    }

    // ---- folded merge/squash epilogue ----
    __syncthreads();   // implicit vmcnt(0) drain per wave -> all stores visible
    if (t == 0) {
        int old = __hip_atomic_fetch_add(&cnt[MODE * NC + c], 1,
                                         __ATOMIC_RELAXED, __HIP_MEMORY_SCOPE_AGENT);
        lastFlag = (old == NCHK - 1) ? 1 : 0;
    }
    __syncthreads();
    if (!lastFlag) return;

    // ===== merger block: merge all 24 chunks of capsule c, squash =====
    if (MODE >= 1) {
        if (t < NB) {
            float z = 0.f;
#pragma unroll
            for (int ch = 0; ch < NCHK; ++ch)
                z += __hip_atomic_load(pz + (size_t)(c * NCHK + ch) * 128 + t,
                                       __ATOMIC_RELAXED, __HIP_MEMORY_SCOPE_AGENT);
            lds[8192 + t] = z;
        }
        __syncthreads();
    }
    float sv[8];
    float pn = 0.f;
    float* pc = ps + (size_t)c * NCHK * 4096;
#pragma unroll
    for (int k = 0; k < 8; ++k) {
        int idx = t + 512 * k;          // o = t&31, b = (t>>5) + 16k
        float s = 0.f;
#pragma unroll
        for (int ch = 0; ch < NCHK; ++ch)
            s += __hip_atomic_load(pc + (size_t)ch * 4096 + idx,
                                   __ATOMIC_RELAXED, __HIP_MEMORY_SCOPE_AGENT);
        float v = (MODE == 0) ? s * (1.0f / 1152.0f) : s / lds[8192 + (idx >> 5)];
        sv[k] = v;
        pn = fmaf(v, v, pn);
    }
    lds[(t >> 5) * 33 + (t & 31)] = pn;   // 16 groups x 32 o
    __syncthreads();
    if (t < 32) {
        float n2 = 0.f;
#pragma unroll
        for (int m = 0; m < 16; ++m) n2 += lds[m * 33 + t];
        lds[1024 + t] = sqrtf(n2) / (1.0f + n2);   // (n2/(1+n2))/sqrt(n2)
    }
    __syncthreads();
    const float ff = lds[1024 + (t & 31)];
#pragma unroll
    for (int k = 0; k < 8; ++k) {
        int idx = t + 512 * k;
        float v = sv[k] * ff;
        if (MODE == 0)      oacc[(size_t)c * 4096 + idx] = v;
        else if (MODE == 1) oacc[(size_t)c * 4096 + idx] += v;
        else                dout[(size_t)c * 4096 + idx] = v;
    }
}

// ------------------------------------------------------------------
extern "C" void kernel_launch(void* const* d_in, const int* in_sizes, int n_in,
                              void* d_out, int out_size, void* d_ws, size_t ws_size,
                              hipStream_t stream)
{
    (void)in_sizes; (void)n_in; (void)out_size; (void)ws_size;
    const float* x = (const float*)d_in[0];
    const float* W = (const float*)d_in[1];
    float* wsf  = (float*)d_ws;
    float* outf = (float*)d_out;

    // ws layout (32-bit units):
    // xts 2,359,296 | ps 983,040 | pz 30,720 | oacc 40,960 | cnt 30  (~13.7 MB)
    unsigned* xts = (unsigned*)d_ws;
    float* ps   = wsf + 2359296;
    float* pz   = ps + 983040;
    float* oacc = pz + 30720;
    int*   cnt  = (int*)(oacc + 40960);

    // zero the per-capsule completion counters (ws is poisoned to 0xAA)
    hipMemsetAsync(cnt, 0, 3 * NC * sizeof(int), stream);

    // iter 0: uniform weights; owner blocks emit xts bf16 planes; folded squash
    pass_y<0><<<240, 512, 0, stream>>>(x, W, xts, oacc, nullptr, ps, pz, cnt);
    // iter 1: softmax(pred . out0); folded squash-accumulate
    pass_y<1><<<240, 512, 0, stream>>>(x, W, xts, oacc, nullptr, ps, pz, cnt);
    // iter 2: softmax(pred . (out0+out1)); folded squash -> d_out
    pass_y<2><<<240, 512, 0, stream>>>(x, W, xts, oacc, outf, ps, pz, cnt);
}

// Round 10
// 67.736 us; speedup vs baseline: 1.1451x; 1.1451x over previous
//
#include <hip/hip_runtime.h>
#include <math.h>

// Problem constants
#define NB 128     // batch
#define NR 1152    // routes
#define NC 10      // capsules
#define NCHK 24    // chunks per capsule (route-chunks of 48)

typedef __attribute__((ext_vector_type(8))) short bf16x8;
typedef __attribute__((ext_vector_type(16))) float f32x16;

__device__ __forceinline__ unsigned pk_bf16(float a, float b) {
    unsigned r;
    asm("v_cvt_pk_bf16_f32 %0, %1, %2" : "=v"(r) : "v"(a), "v"(b));
    return r;
}

// ------------------------------------------------------------------
// pass_z: fused bf16x3 + 32x32x16 MFMA pred + route reduction + folded
// merge/squash epilogue.  Round-9 structure, but cross-chunk reduction is
// done with agent-scope atomicAdd into a per-capsule 16KB accumulator
// (sbuf[c][128][32], zbuf[c][128]) instead of per-chunk buffers -> the
// last-block merger reads 16KB, not 393KB.
// Grid 240 = (10 c x 24 rch of 48 routes), XCD-chunked. 512 thr = 8 waves:
// wave = (h = route-quarter of 12, bp = batch-half).
// A = W (M=o), B = x (N=b). C: col(l&31)=b, row(reg&3)+8*(reg>>2)+4*hi1=o.
// MODE 0: uniform sum; x read direct; owner blocks write xts bf16 planes.
// MODE 1/2: x fragments from xts; d = pred.ov, e = exp(d-20), Z += e,
//           acc += e*pred.
// Epilogue: LDS 4-slice merge -> atomicAdd chunk partial into sbuf/zbuf;
// __syncthreads (drains vmcnt); one fetch_add; last block (old==23) loads
// the 16KB sums (agent atomic loads), squashes over batch, writes
// oacc (M0) / oacc+= (M1) / dout (M2).
// ------------------------------------------------------------------
template<int MODE>
__global__ __launch_bounds__(512, 2) void pass_z(const float* __restrict__ x,
                                                 const float* __restrict__ W,
                                                 unsigned* __restrict__ xts,
                                                 float* __restrict__ oacc,
                                                 float* __restrict__ dout,
                                                 float* __restrict__ sbuf,
                                                 float* __restrict__ zbuf,
                                                 int* __restrict__ cnt)
{
    __shared__ float lds[16384];   // 64 KB
    __shared__ int lastFlag;
    const int pb = blockIdx.x;
    const int lin = (pb & 7) * 30 + (pb >> 3);   // chunked XCD swizzle (240 = 8*30)
    const int rch = lin / 10;
    const int c   = lin - rch * 10;
    const int t = threadIdx.x;
    const int w = t >> 6, l = t & 63;
    const int h = w >> 1, bp = w & 1;
    const int lo5 = l & 31, hi1 = l >> 5;
    const int r0 = rch * 48 + h * 12;

    if (MODE >= 1) {
        for (int idx = t; idx < 4096; idx += 512)
            lds[(idx >> 5) * 33 + (idx & 31)] = oacc[(size_t)c * 4096 + idx];
    }
    __syncthreads();

    float ov0[16], ov1[16];
    if (MODE >= 1) {
#pragma unroll
        for (int j = 0; j < 16; ++j) {
            int orow = (j & 3) + 8 * (j >> 2) + 4 * hi1;
            ov0[j] = lds[(bp * 64 + lo5) * 33 + orow];
            ov1[j] = lds[(bp * 64 + 32 + lo5) * 33 + orow];
        }
    }

    f32x16 acc0, acc1, zz;
#pragma unroll
    for (int j = 0; j < 16; ++j) { acc0[j] = 0.f; acc1[j] = 0.f; zz[j] = 0.f; }
    float Z0 = 0.f, Z1 = 0.f;

    // W element (r, i=hi1*8+j, o=lo5)
    const float* wb  = W + ((size_t)(c * NR + r0) * 16 + hi1 * 8) * 32 + lo5;
    // direct-x pointers (MODE 0)
    const float* xp0 = x + ((size_t)(bp * 64 + lo5) * NR + r0) * 16 + hi1 * 8;
    const float* xp1 = x + ((size_t)(bp * 64 + 32 + lo5) * NR + r0) * 16 + hi1 * 8;
    // xts uint4-unit addressing: ((r*2+hi1)*2 + plane)*128 + b
    uint4* xt4 = (uint4*)xts;
    const int bq0 = bp * 64 + lo5, bq1 = bq0 + 32;

    for (int rr = 0; rr < 12; ++rr) {
        // ---- W fragment: 8 lane-coalesced f32 -> hi/lo bf16 planes ----
        float wv[8];
#pragma unroll
        for (int j = 0; j < 8; ++j) wv[j] = wb[(size_t)rr * 512 + j * 32];
        union U { uint4 q; unsigned u[4]; bf16x8 v; };
        U Ah, Al, Xh0, Xl0, Xh1, Xl1;
#pragma unroll
        for (int j = 0; j < 4; ++j) Ah.u[j] = pk_bf16(wv[2*j], wv[2*j+1]);
#pragma unroll
        for (int j = 0; j < 4; ++j) {
            float g0 = __uint_as_float(Ah.u[j] << 16);
            float g1 = __uint_as_float(Ah.u[j] & 0xffff0000u);
            Al.u[j] = pk_bf16(wv[2*j] - g0, wv[2*j+1] - g1);
        }
        // ---- x fragments ----
        const size_t rb4 = ((size_t)((r0 + rr) * 2 + hi1) * 2) * 128;
        if (MODE == 0) {
            float4 u0 = *(const float4*)(xp0 + rr * 16);
            float4 u1 = *(const float4*)(xp0 + rr * 16 + 4);
            float4 v0 = *(const float4*)(xp1 + rr * 16);
            float4 v1 = *(const float4*)(xp1 + rr * 16 + 4);
            float xv0[8] = {u0.x,u0.y,u0.z,u0.w, u1.x,u1.y,u1.z,u1.w};
            float xv1[8] = {v0.x,v0.y,v0.z,v0.w, v1.x,v1.y,v1.z,v1.w};
#pragma unroll
            for (int j = 0; j < 4; ++j) Xh0.u[j] = pk_bf16(xv0[2*j], xv0[2*j+1]);
#pragma unroll
            for (int j = 0; j < 4; ++j) {
                float g0 = __uint_as_float(Xh0.u[j] << 16);
                float g1 = __uint_as_float(Xh0.u[j] & 0xffff0000u);
                Xl0.u[j] = pk_bf16(xv0[2*j] - g0, xv0[2*j+1] - g1);
            }
#pragma unroll
            for (int j = 0; j < 4; ++j) Xh1.u[j] = pk_bf16(xv1[2*j], xv1[2*j+1]);
#pragma unroll
            for (int j = 0; j < 4; ++j) {
                float g0 = __uint_as_float(Xh1.u[j] << 16);
                float g1 = __uint_as_float(Xh1.u[j] & 0xffff0000u);
                Xl1.u[j] = pk_bf16(xv1[2*j] - g0, xv1[2*j+1] - g1);
            }
            // distributed xts write: this block owns routes (h*12+rr)%10 == c
            if (((h * 12 + rr) % 10) == c) {
                xt4[rb4 + bq0]       = Xh0.q;
                xt4[rb4 + 128 + bq0] = Xl0.q;
                xt4[rb4 + bq1]       = Xh1.q;
                xt4[rb4 + 128 + bq1] = Xl1.q;
            }
        } else {
            Xh0.q = xt4[rb4 + bq0];
            Xl0.q = xt4[rb4 + 128 + bq0];
            Xh1.q = xt4[rb4 + bq1];
            Xl1.q = xt4[rb4 + 128 + bq1];
        }

        if (MODE == 0) {
            acc0 = __builtin_amdgcn_mfma_f32_32x32x16_bf16(Ah.v, Xh0.v, acc0, 0, 0, 0);
            acc0 = __builtin_amdgcn_mfma_f32_32x32x16_bf16(Al.v, Xh0.v, acc0, 0, 0, 0);
            acc0 = __builtin_amdgcn_mfma_f32_32x32x16_bf16(Ah.v, Xl0.v, acc0, 0, 0, 0);
            acc1 = __builtin_amdgcn_mfma_f32_32x32x16_bf16(Ah.v, Xh1.v, acc1, 0, 0, 0);
            acc1 = __builtin_amdgcn_mfma_f32_32x32x16_bf16(Al.v, Xh1.v, acc1, 0, 0, 0);
            acc1 = __builtin_amdgcn_mfma_f32_32x32x16_bf16(Ah.v, Xl1.v, acc1, 0, 0, 0);
        } else {
            f32x16 q0, q1;
            q0 = __builtin_amdgcn_mfma_f32_32x32x16_bf16(Ah.v, Xh0.v, zz, 0, 0, 0);
            q1 = __builtin_amdgcn_mfma_f32_32x32x16_bf16(Ah.v, Xh1.v, zz, 0, 0, 0);
            q0 = __builtin_amdgcn_mfma_f32_32x32x16_bf16(Al.v, Xh0.v, q0, 0, 0, 0);
            q1 = __builtin_amdgcn_mfma_f32_32x32x16_bf16(Al.v, Xh1.v, q1, 0, 0, 0);
            q0 = __builtin_amdgcn_mfma_f32_32x32x16_bf16(Ah.v, Xl0.v, q0, 0, 0, 0);
            q1 = __builtin_amdgcn_mfma_f32_32x32x16_bf16(Ah.v, Xl1.v, q1, 0, 0, 0);
            float d0 = 0.f, d1 = 0.f;
#pragma unroll
            for (int j = 0; j < 16; ++j) {
                d0 = fmaf(q0[j], ov0[j], d0);
                d1 = fmaf(q1[j], ov1[j], d1);
            }
            d0 += __shfl_xor(d0, 32);
            d1 += __shfl_xor(d1, 32);
            float e0 = __expf(d0 - 20.0f);
            float e1 = __expf(d1 - 20.0f);
            Z0 += e0; Z1 += e1;
#pragma unroll
            for (int j = 0; j < 16; ++j) {
                acc0[j] = fmaf(e0, q0[j], acc0[j]);
                acc1[j] = fmaf(e1, q1[j], acc1[j]);
            }
        }
    }

    // ---- 8-wave LDS merge (4 h-slices; b-halves disjoint) ----
    const int b0 = bp * 64 + lo5, b1 = b0 + 32;
    __syncthreads();
#pragma unroll
    for (int j = 0; j < 16; ++j) {
        int orow = (j & 3) + 8 * (j >> 2) + 4 * hi1;
        lds[h * 4096 + b0 * 32 + (orow ^ lo5)] = acc0[j];
        lds[h * 4096 + b1 * 32 + (orow ^ lo5)] = acc1[j];
    }
    __syncthreads();
    // chunk partial -> per-capsule accumulator via agent-scope atomicAdd
    float* sc = sbuf + (size_t)c * 4096;
    for (int idx = t; idx < 4096; idx += 512) {
        int b = idx >> 5, o = idx & 31;
        float s = 0.f;
#pragma unroll
        for (int hh = 0; hh < 4; ++hh)
            s += lds[hh * 4096 + b * 32 + (o ^ (b & 31))];
        (void)__hip_atomic_fetch_add(sc + idx, s, __ATOMIC_RELAXED,
                                     __HIP_MEMORY_SCOPE_AGENT);
    }
    if (MODE >= 1) {
        __syncthreads();
        if (l < 32) {
            lds[h * 128 + bp * 64 + lo5] = Z0;
            lds[h * 128 + bp * 64 + 32 + lo5] = Z1;
        }
        __syncthreads();
        if (t < 128) {
            float z = lds[t] + lds[128 + t] + lds[256 + t] + lds[384 + t];
            (void)__hip_atomic_fetch_add(zbuf + (size_t)c * 128 + t, z,
                                         __ATOMIC_RELAXED, __HIP_MEMORY_SCOPE_AGENT);
        }
    }

    // ---- completion handshake ----
    __syncthreads();   // per-wave vmcnt(0) drain -> all adds at coherence point
    if (t == 0) {
        int old = __hip_atomic_fetch_add(&cnt[c], 1,
                                         __ATOMIC_RELAXED, __HIP_MEMORY_SCOPE_AGENT);
        lastFlag = (old == NCHK - 1) ? 1 : 0;
    }
    __syncthreads();
    if (!lastFlag) return;

    // ===== merger block: read 16KB summed s (+512B z), squash, write =====
    if (MODE >= 1) {
        if (t < NB) {
            lds[8192 + t] = __hip_atomic_load(zbuf + (size_t)c * 128 + t,
                                              __ATOMIC_RELAXED, __HIP_MEMORY_SCOPE_AGENT);
        }
        __syncthreads();
    }
    float sv[8];
    float pn = 0.f;
#pragma unroll
    for (int k = 0; k < 8; ++k) {
        int idx = t + 512 * k;          // o = t&31, b-groups
        float s = __hip_atomic_load(sc + idx, __ATOMIC_RELAXED,
                                    __HIP_MEMORY_SCOPE_AGENT);
        float v = (MODE == 0) ? s * (1.0f / 1152.0f) : s / lds[8192 + (idx >> 5)];
        sv[k] = v;
        pn = fmaf(v, v, pn);
    }
    lds[(t >> 5) * 33 + (t & 31)] = pn;   // 16 groups x 32 o
    __syncthreads();
    if (t < 32) {
        float n2 = 0.f;
#pragma unroll
        for (int m = 0; m < 16; ++m) n2 += lds[m * 33 + t];
        lds[1024 + t] = sqrtf(n2) / (1.0f + n2);   // (n2/(1+n2))/sqrt(n2)
    }
    __syncthreads();
    const float ff = lds[1024 + (t & 31)];
#pragma unroll
    for (int k = 0; k < 8; ++k) {
        int idx = t + 512 * k;
        float v = sv[k] * ff;
        if (MODE == 0)      oacc[(size_t)c * 4096 + idx] = v;
        else if (MODE == 1) oacc[(size_t)c * 4096 + idx] += v;
        else                dout[(size_t)c * 4096 + idx] = v;
    }
}

// ------------------------------------------------------------------
extern "C" void kernel_launch(void* const* d_in, const int* in_sizes, int n_in,
                              void* d_out, int out_size, void* d_ws, size_t ws_size,
                              hipStream_t stream)
{
    (void)in_sizes; (void)n_in; (void)out_size; (void)ws_size;
    const float* x = (const float*)d_in[0];
    const float* W = (const float*)d_in[1];
    float* wsf  = (float*)d_ws;
    float* outf = (float*)d_out;

    // ws layout (32-bit units):
    // xts 2,359,296 | sbuf 3x40,960 | zbuf 3x1,280 | cnt 32 | oacc 40,960
    unsigned* xts = (unsigned*)d_ws;
    float* sb   = wsf + 2359296;
    float* zb   = sb + 3 * 40960;
    int*   cnt  = (int*)(zb + 3 * 1280);
    float* oacc = (float*)(cnt + 32);

    // zero accumulators + counters (ws is poisoned to 0xAA once)
    hipMemsetAsync(sb, 0, (size_t)(3 * 40960 + 3 * 1280 + 32) * 4, stream);

    // iter 0: uniform; owner blocks emit xts bf16 planes; folded squash
    pass_z<0><<<240, 512, 0, stream>>>(x, W, xts, oacc, nullptr,
                                       sb, zb, cnt);
    // iter 1: softmax(pred . out0); folded squash-accumulate
    pass_z<1><<<240, 512, 0, stream>>>(x, W, xts, oacc, nullptr,
                                       sb + 40960, zb + 1280, cnt + NC);
    // iter 2: softmax(pred . (out0+out1)); folded squash -> d_out
    pass_z<2><<<240, 512, 0, stream>>>(x, W, xts, oacc, outf,
                                       sb + 2 * 40960, zb + 2 * 1280, cnt + 2 * NC);
}